// Round 1
// baseline (38.223 us; speedup 1.0000x reference)
//
#include <hip/hip_runtime.h>

// DCN cross layers, fused closed form.
// out[r,d] = x[r,d] * (1 + sum_i s_i * W[i,d]) + sum_i b[i,d]
// s_0 = sum_d x[r,d];  s_{i+1} = s_i * (1 + dot(x_r, W[i])) + sum_d b[i,d]

constexpr int Bn = 8192;
constexpr int D = 2048;
constexpr int L = 4;
constexpr int THREADS = 256;
constexpr int VEC = 4;
constexpr int PASSES = D / (THREADS * VEC); // 2
constexpr int NSUMS = 1 + 2 * L;            // T, A0..A3, B0..B3 = 9

__global__ __launch_bounds__(THREADS) void cross_layer_kernel(
    const float* __restrict__ x,
    const float* __restrict__ W,
    const float* __restrict__ b,
    float* __restrict__ out)
{
    const int row = blockIdx.x;
    const int tid = threadIdx.x;
    const float* xr = x + (size_t)row * D;

    float4 xv[PASSES];
    float4 wv[L][PASSES];
    float4 bs[PASSES];        // per-element sum over layers of b
    float sums[NSUMS];
#pragma unroll
    for (int k = 0; k < NSUMS; ++k) sums[k] = 0.f;

#pragma unroll
    for (int p = 0; p < PASSES; ++p) {
        const int d = p * (THREADS * VEC) + tid * VEC;
        xv[p] = *reinterpret_cast<const float4*>(xr + d);
        sums[0] += xv[p].x + xv[p].y + xv[p].z + xv[p].w;
        float4 bsum = make_float4(0.f, 0.f, 0.f, 0.f);
#pragma unroll
        for (int i = 0; i < L; ++i) {
            float4 w = *reinterpret_cast<const float4*>(W + i * D + d);
            wv[i][p] = w;
            sums[1 + i] += xv[p].x * w.x + xv[p].y * w.y
                         + xv[p].z * w.z + xv[p].w * w.w;
            float4 bb = *reinterpret_cast<const float4*>(b + i * D + d);
            bsum.x += bb.x; bsum.y += bb.y; bsum.z += bb.z; bsum.w += bb.w;
            sums[1 + L + i] += bb.x + bb.y + bb.z + bb.w;
        }
        bs[p] = bsum;
    }

    // Wave-level reduction (64 lanes) of all 9 sums.
#pragma unroll
    for (int k = 0; k < NSUMS; ++k) {
#pragma unroll
        for (int off = 32; off > 0; off >>= 1)
            sums[k] += __shfl_down(sums[k], off, 64);
    }

    // Cross-wave reduction via LDS (4 waves).
    __shared__ float red[4][NSUMS];
    const int lane = tid & 63;
    const int wid = tid >> 6;
    if (lane == 0) {
#pragma unroll
        for (int k = 0; k < NSUMS; ++k) red[wid][k] = sums[k];
    }
    __syncthreads();

    float tot[NSUMS];
#pragma unroll
    for (int k = 0; k < NSUMS; ++k)
        tot[k] = red[0][k] + red[1][k] + red[2][k] + red[3][k];

    // Scalar recurrence (uniform across block).
    // tot[0]=T, tot[1..4]=A_0..A_3, tot[5..8]=B_0..B_3
    float s[L];
    s[0] = tot[0];
#pragma unroll
    for (int i = 1; i < L; ++i)
        s[i] = s[i - 1] * (1.f + tot[i]) + tot[L + i];   // A_{i-1}=tot[i], B_{i-1}=tot[4+i]

    float* outr = out + (size_t)row * D;
#pragma unroll
    for (int p = 0; p < PASSES; ++p) {
        const int d = p * (THREADS * VEC) + tid * VEC;
        float4 o;
        float cx = 1.f, cy = 1.f, cz = 1.f, cw = 1.f;
#pragma unroll
        for (int i = 0; i < L; ++i) {
            cx += s[i] * wv[i][p].x;
            cy += s[i] * wv[i][p].y;
            cz += s[i] * wv[i][p].z;
            cw += s[i] * wv[i][p].w;
        }
        o.x = xv[p].x * cx + bs[p].x;
        o.y = xv[p].y * cy + bs[p].y;
        o.z = xv[p].z * cz + bs[p].z;
        o.w = xv[p].w * cw + bs[p].w;
        *reinterpret_cast<float4*>(outr + d) = o;
    }
}

extern "C" void kernel_launch(void* const* d_in, const int* in_sizes, int n_in,
                              void* d_out, int out_size, void* d_ws, size_t ws_size,
                              hipStream_t stream) {
    const float* x = (const float*)d_in[0];
    const float* W = (const float*)d_in[1];
    const float* b = (const float*)d_in[2];
    float* out = (float*)d_out;
    cross_layer_kernel<<<Bn, THREADS, 0, stream>>>(x, W, b, out);
}

// Round 2
// 27.898 us; speedup vs baseline: 1.3701x; 1.3701x over previous
//
#include <hip/hip_runtime.h>

// DCN cross layers, fused closed form with persistent blocks.
// out[r,d] = x[r,d] * (1 + sum_i s_i * W[i,d]) + bsum[d]
// s_0 = T = sum_d x[r,d];  s_{i} = s_{i-1} * (1 + A_{i-1}) + B_{i-1}
// A_j = dot(x_r, W[j]),  B_j = sum_d b[j,d],  bsum[d] = sum_j b[j,d]
//
// Each block loads W/b ONCE (registers), then processes RPB rows with
// prefetch, so steady-state traffic is just x-in + out-write (HBM-bound).

constexpr int Bn = 8192;
constexpr int D = 2048;
constexpr int L = 4;
constexpr int THREADS = 256;
constexpr int VEC = 4;
constexpr int PASSES = D / (THREADS * VEC); // 2
constexpr int RPB = 4;                      // rows per block
constexpr int GRID = Bn / RPB;              // 2048 = 8 blocks/CU

__global__ __launch_bounds__(THREADS) void cross_layer_kernel(
    const float* __restrict__ x,
    const float* __restrict__ W,
    const float* __restrict__ b,
    float* __restrict__ out)
{
    const int tid = threadIdx.x;
    const int lane = tid & 63;
    const int wid = tid >> 6;

    __shared__ float red[4][8];

    // ---- prologue: block-invariant W and b ----
    float4 wv[L][PASSES];   // W fragments, held for all rows
    float4 bs[PASSES];      // elementwise sum over layers of b
    float bred[3];          // partial sums of b per layer 0..2 (B_3 unused)
    bred[0] = bred[1] = bred[2] = 0.f;

#pragma unroll
    for (int p = 0; p < PASSES; ++p) {
        const int d = p * (THREADS * VEC) + tid * VEC;
        float4 bsum = make_float4(0.f, 0.f, 0.f, 0.f);
#pragma unroll
        for (int i = 0; i < L; ++i) {
            wv[i][p] = *reinterpret_cast<const float4*>(W + i * D + d);
            float4 bb = *reinterpret_cast<const float4*>(b + i * D + d);
            bsum.x += bb.x; bsum.y += bb.y; bsum.z += bb.z; bsum.w += bb.w;
            if (i < 3) bred[i] += bb.x + bb.y + bb.z + bb.w;
        }
        bs[p] = bsum;
    }

    // Block-reduce B_0..B_2.
#pragma unroll
    for (int k = 0; k < 3; ++k) {
#pragma unroll
        for (int off = 32; off > 0; off >>= 1)
            bred[k] += __shfl_down(bred[k], off, 64);
    }
    if (lane == 0) {
#pragma unroll
        for (int k = 0; k < 3; ++k) red[wid][k] = bred[k];
    }
    __syncthreads();
    float Bsc[3];
#pragma unroll
    for (int k = 0; k < 3; ++k)
        Bsc[k] = red[0][k] + red[1][k] + red[2][k] + red[3][k];

    // ---- row loop with x prefetch ----
    float4 xv[PASSES], xn[PASSES];
    {
        const float* xr = x + (size_t)blockIdx.x * D;
#pragma unroll
        for (int p = 0; p < PASSES; ++p)
            xv[p] = *reinterpret_cast<const float4*>(xr + p * (THREADS * VEC) + tid * VEC);
    }

    for (int k = 0; k < RPB; ++k) {
        if (k + 1 < RPB) {
            const float* xr = x + (size_t)(blockIdx.x + GRID * (k + 1)) * D;
#pragma unroll
            for (int p = 0; p < PASSES; ++p)
                xn[p] = *reinterpret_cast<const float4*>(xr + p * (THREADS * VEC) + tid * VEC);
        }

        // 4 row sums: T, A0, A1, A2
        float sm[4];
        sm[0] = sm[1] = sm[2] = sm[3] = 0.f;
#pragma unroll
        for (int p = 0; p < PASSES; ++p) {
            sm[0] += xv[p].x + xv[p].y + xv[p].z + xv[p].w;
#pragma unroll
            for (int i = 0; i < 3; ++i) {
                sm[1 + i] += xv[p].x * wv[i][p].x + xv[p].y * wv[i][p].y
                           + xv[p].z * wv[i][p].z + xv[p].w * wv[i][p].w;
            }
        }
#pragma unroll
        for (int q = 0; q < 4; ++q) {
#pragma unroll
            for (int off = 32; off > 0; off >>= 1)
                sm[q] += __shfl_down(sm[q], off, 64);
        }
        __syncthreads();   // protect red[] from previous iteration's reads
        if (lane == 0) {
#pragma unroll
            for (int q = 0; q < 4; ++q) red[wid][q] = sm[q];
        }
        __syncthreads();

        const float T  = red[0][0] + red[1][0] + red[2][0] + red[3][0];
        float A[3];
#pragma unroll
        for (int q = 0; q < 3; ++q)
            A[q] = red[0][1 + q] + red[1][1 + q] + red[2][1 + q] + red[3][1 + q];

        float s[L];
        s[0] = T;
#pragma unroll
        for (int i = 1; i < L; ++i)
            s[i] = s[i - 1] * (1.f + A[i - 1]) + Bsc[i - 1];

        // output
        float* outr = out + (size_t)(blockIdx.x + GRID * k) * D;
#pragma unroll
        for (int p = 0; p < PASSES; ++p) {
            float cx = 1.f, cy = 1.f, cz = 1.f, cw = 1.f;
#pragma unroll
            for (int i = 0; i < L; ++i) {
                cx += s[i] * wv[i][p].x;
                cy += s[i] * wv[i][p].y;
                cz += s[i] * wv[i][p].z;
                cw += s[i] * wv[i][p].w;
            }
            float4 o;
            o.x = xv[p].x * cx + bs[p].x;
            o.y = xv[p].y * cy + bs[p].y;
            o.z = xv[p].z * cz + bs[p].z;
            o.w = xv[p].w * cw + bs[p].w;
            *reinterpret_cast<float4*>(outr + p * (THREADS * VEC) + tid * VEC) = o;
        }

#pragma unroll
        for (int p = 0; p < PASSES; ++p) xv[p] = xn[p];
    }
}

extern "C" void kernel_launch(void* const* d_in, const int* in_sizes, int n_in,
                              void* d_out, int out_size, void* d_ws, size_t ws_size,
                              hipStream_t stream) {
    const float* x = (const float*)d_in[0];
    const float* W = (const float*)d_in[1];
    const float* b = (const float*)d_in[2];
    float* out = (float*)d_out;
    cross_layer_kernel<<<GRID, THREADS, 0, stream>>>(x, W, b, out);
}